// Round 1
// baseline (13453.029 us; speedup 1.0000x reference)
//
#include <hip/hip_runtime.h>
#include <math.h>

#define H     128
#define NPATH 8192
#define TLEN  512
#define BP    32            // paths per block
#define WS    132           // padded row stride (floats) for weights and acts
#define NTHR  256

// LDS layout (float offsets)
#define OFF_WF2   0                    // fw2 [128][WS]
#define OFF_WG2   (OFF_WF2 + H*WS)     // gw2 [128][WS]
#define OFF_ACT   (OFF_WG2 + H*WS)     // act [BP][WS]
#define OFF_FW1   (OFF_ACT + BP*WS)    // fw1 [3][128]
#define OFF_FB1   (OFF_FW1 + 3*H)
#define OFF_FB2   (OFF_FB1 + H)
#define OFF_FW3T  (OFF_FB2 + H)        // fw3^T [2][128]
#define OFF_GW1   (OFF_FW3T + 2*H)     // gw1 [2][128]
#define OFF_GB1   (OFF_GW1 + 2*H)
#define OFF_GB2   (OFF_GB1 + H)
#define OFF_GW3T  (OFF_GB2 + H)        // gw3^T [2][128]
#define OFF_FB3   (OFF_GW3T + 2*H)     // [4]
#define OFF_GB3   (OFF_FB3 + 4)        // [4]
#define OFF_Y     (OFF_GB3 + 4)        // y_cur [BP][2]
#define SMEM_FLOATS (OFF_Y + BP*2)
#define SMEM_BYTES  (SMEM_FLOATS * 4)  // = 159008 B < 160 KiB

__device__ __forceinline__ float bf2f(unsigned short v){
  return __uint_as_float(((unsigned)v) << 16);
}
__device__ __forceinline__ unsigned short f2bf(float f){   // round-to-nearest-even
  unsigned u = __float_as_uint(f);
  return (unsigned short)((u + 0x7fffu + ((u >> 16) & 1u)) >> 16);
}
__device__ __forceinline__ float ldany(const void* p, long long i, bool isbf){
  return isbf ? bf2f(((const unsigned short*)p)[i]) : ((const float*)p)[i];
}
__device__ __forceinline__ float fsig(float x){
  return __builtin_amdgcn_rcpf(1.0f + __expf(-x));
}
__device__ __forceinline__ float fsilu(float x){ return x * fsig(x); }
__device__ __forceinline__ float fsilud(float x){
  float s = fsig(x); return s * (1.0f + x * (1.0f - s));
}
__device__ __forceinline__ float fsoftplus(float x){
  if (x > 15.0f) return x;
  return __logf(1.0f + __expf(x));
}
__device__ __forceinline__ void red16x4(float& a, float& b, float& c, float& d){
  #pragma unroll
  for (int m = 8; m; m >>= 1){
    a += __shfl_xor(a, m, 16);
    b += __shfl_xor(b, m, 16);
    c += __shfl_xor(c, m, 16);
    d += __shfl_xor(d, m, 16);
  }
}

// z[j] = bias[n0+j] + sum_k act[p][k] * W[k][n0+j], for 2 paths.
__device__ __forceinline__ void fwd_mm(const float* __restrict__ sm, int woff, int boff,
                                       int p0, int p1, int n0,
                                       float za[8], float zb[8])
{
  #pragma unroll
  for (int j = 0; j < 8; ++j){ float b = sm[boff + n0 + j]; za[j] = b; zb[j] = b; }
  const float* wp = sm + woff + n0;
  const float* aa = sm + OFF_ACT + p0 * WS;
  const float* ab = sm + OFF_ACT + p1 * WS;
  #pragma unroll 4
  for (int k = 0; k < H; ++k){
    float a0 = aa[k], a1 = ab[k];
    float4 w0 = *(const float4*)(wp + k * WS);
    float4 w1 = *(const float4*)(wp + k * WS + 4);
    za[0] += a0 * w0.x; za[1] += a0 * w0.y; za[2] += a0 * w0.z; za[3] += a0 * w0.w;
    za[4] += a0 * w1.x; za[5] += a0 * w1.y; za[6] += a0 * w1.z; za[7] += a0 * w1.w;
    zb[0] += a1 * w0.x; zb[1] += a1 * w0.y; zb[2] += a1 * w0.z; zb[3] += a1 * w0.w;
    zb[4] += a1 * w1.x; zb[5] += a1 * w1.y; zb[6] += a1 * w1.z; zb[7] += a1 * w1.w;
  }
}

__global__ __launch_bounds__(NTHR, 1)
void GeneratorSDE_kernel(const void* __restrict__ y0, const void* __restrict__ ts,
                         const void* __restrict__ dW,
                         const void* __restrict__ fw1, const void* __restrict__ fb1,
                         const void* __restrict__ fw2, const void* __restrict__ fb2,
                         const void* __restrict__ fw3, const void* __restrict__ fb3,
                         const void* __restrict__ gw1, const void* __restrict__ gb1,
                         const void* __restrict__ gw2, const void* __restrict__ gb2,
                         const void* __restrict__ gw3, const void* __restrict__ gb3,
                         void* __restrict__ out)
{
  extern __shared__ float sm[];
  const int tid = threadIdx.x;
  const int ng  = tid & 15;        // neuron group: owns n0..n0+7
  const int pp  = tid >> 4;        // 0..15
  const int p0  = pp, p1 = pp + 16;
  const int n0  = ng * 8;
  const int gpb = blockIdx.x * BP;

  // dtype probe: fp32 ts[1] == 1.0f bit pattern; bf16 packs (2.0,3.0) there.
  const bool isbf = (((const unsigned*)ts)[1] != 0x3f800000u);

  // ---- stage weights into LDS (fp32) ----
  for (int e = tid; e < H * H; e += NTHR)
    sm[OFF_WF2 + (e >> 7) * WS + (e & 127)] = ldany(fw2, e, isbf);
  for (int e = tid; e < H * H; e += NTHR)
    sm[OFF_WG2 + (e >> 7) * WS + (e & 127)] = ldany(gw2, e, isbf);
  for (int e = tid; e < 3 * H; e += NTHR) sm[OFF_FW1 + e] = ldany(fw1, e, isbf);
  for (int e = tid; e < 2 * H; e += NTHR) sm[OFF_GW1 + e] = ldany(gw1, e, isbf);
  for (int e = tid; e < H; e += NTHR){
    sm[OFF_FB1 + e] = ldany(fb1, e, isbf);
    sm[OFF_FB2 + e] = ldany(fb2, e, isbf);
    sm[OFF_GB1 + e] = ldany(gb1, e, isbf);
    sm[OFF_GB2 + e] = ldany(gb2, e, isbf);
    sm[OFF_FW3T + e]     = ldany(fw3, 2 * e + 0, isbf);
    sm[OFF_FW3T + H + e] = ldany(fw3, 2 * e + 1, isbf);
    sm[OFF_GW3T + e]     = ldany(gw3, 2 * e + 0, isbf);
    sm[OFF_GW3T + H + e] = ldany(gw3, 2 * e + 1, isbf);
  }
  if (tid < 2){ sm[OFF_FB3 + tid] = ldany(fb3, tid, isbf);
                sm[OFF_GB3 + tid] = ldany(gb3, tid, isbf); }
  // y0 -> LDS, and emit t=0 output row
  if (tid < BP){
    int gp = gpb + tid;
    float a = ldany(y0, (long long)gp * 2 + 0, isbf);
    float b = ldany(y0, (long long)gp * 2 + 1, isbf);
    sm[OFF_Y + tid * 2 + 0] = a; sm[OFF_Y + tid * 2 + 1] = b;
    size_t r = (size_t)gp * TLEN;
    if (isbf) ((unsigned*)out)[r] = (unsigned)f2bf(a) | ((unsigned)f2bf(b) << 16);
    else      ((float2*)out)[r] = make_float2(a, b);
  }
  __syncthreads();

  for (int t = 0; t < TLEN - 1; ++t){
    // step constants
    float tc = ldany(ts, t, isbf), tn = ldany(ts, t + 1, isbf);
    float dt = tn - tc;
    float sqdt = sqrtf(dt);
    long long dwb0 = ((long long)t * NPATH + (gpb + p0)) * 2;
    long long dwb1 = ((long long)t * NPATH + (gpb + p1)) * 2;
    float dw00 = ldany(dW, dwb0 + 0, isbf) * sqdt;
    float dw01 = ldany(dW, dwb0 + 1, isbf) * sqdt;
    float dw10 = ldany(dW, dwb1 + 0, isbf) * sqdt;
    float dw11 = ldany(dW, dwb1 + 1, isbf) * sqdt;
    float v00 = 0.5f * (dw00 * dw00 - dt), v01 = 0.5f * (dw01 * dw01 - dt);
    float v10 = 0.5f * (dw10 * dw10 - dt), v11 = 0.5f * (dw11 * dw11 - dt);

    float ya0 = sm[OFF_Y + p0 * 2], ya1 = sm[OFF_Y + p0 * 2 + 1];
    float yb0 = sm[OFF_Y + p1 * 2], yb1 = sm[OFF_Y + p1 * 2 + 1];
    float xa2 = ya0 - ya1, xb2 = yb0 - yb1;

    // ---- A: drift layer 1 -> act ----
    {
      float ha[8], hb[8];
      #pragma unroll
      for (int j = 0; j < 8; ++j){
        int n = n0 + j;
        float w0 = sm[OFF_FW1 + n], w1 = sm[OFF_FW1 + H + n], w2 = sm[OFF_FW1 + 2 * H + n];
        float b  = sm[OFF_FB1 + n];
        ha[j] = fsilu(b + ya0 * w0 + ya1 * w1 + xa2 * w2);
        hb[j] = fsilu(b + yb0 * w0 + yb1 * w1 + xb2 * w2);
      }
      *(float4*)&sm[OFF_ACT + p0 * WS + n0]     = make_float4(ha[0], ha[1], ha[2], ha[3]);
      *(float4*)&sm[OFF_ACT + p0 * WS + n0 + 4] = make_float4(ha[4], ha[5], ha[6], ha[7]);
      *(float4*)&sm[OFF_ACT + p1 * WS + n0]     = make_float4(hb[0], hb[1], hb[2], hb[3]);
      *(float4*)&sm[OFF_ACT + p1 * WS + n0 + 4] = make_float4(hb[4], hb[5], hb[6], hb[7]);
    }
    __syncthreads();                                   // bar 1

    // ---- B: drift layer 2 + head ----
    float f0a, f1a, f0b, f1b;
    {
      float h2a[8], h2b[8];
      fwd_mm(sm, OFF_WF2, OFF_FB2, p0, p1, n0, h2a, h2b);
      float pf0a = 0, pf1a = 0, pf0b = 0, pf1b = 0;
      #pragma unroll
      for (int j = 0; j < 8; ++j){
        int n = n0 + j;
        float s_a = fsilu(h2a[j]), s_b = fsilu(h2b[j]);
        float w0 = sm[OFF_FW3T + n], w1 = sm[OFF_FW3T + H + n];
        pf0a += s_a * w0; pf1a += s_a * w1;
        pf0b += s_b * w0; pf1b += s_b * w1;
      }
      red16x4(pf0a, pf1a, pf0b, pf1b);
      f0a = pf0a + sm[OFF_FB3]; f1a = pf1a + sm[OFF_FB3 + 1];
      f0b = pf0b + sm[OFF_FB3]; f1b = pf1b + sm[OFF_FB3 + 1];
    }
    __syncthreads();                                   // bar 2 (act free)

    // ---- C: diffusion layer 1 -> act (keep z1 in regs) ----
    float z1a[8], z1b[8];
    {
      float aa[8], ab[8];
      #pragma unroll
      for (int j = 0; j < 8; ++j){
        int n = n0 + j;
        float w0 = sm[OFF_GW1 + n], w1 = sm[OFF_GW1 + H + n], b = sm[OFF_GB1 + n];
        z1a[j] = b + ya0 * w0 + ya1 * w1;
        z1b[j] = b + yb0 * w0 + yb1 * w1;
        aa[j] = fsilu(z1a[j]); ab[j] = fsilu(z1b[j]);
      }
      *(float4*)&sm[OFF_ACT + p0 * WS + n0]     = make_float4(aa[0], aa[1], aa[2], aa[3]);
      *(float4*)&sm[OFF_ACT + p0 * WS + n0 + 4] = make_float4(aa[4], aa[5], aa[6], aa[7]);
      *(float4*)&sm[OFF_ACT + p1 * WS + n0]     = make_float4(ab[0], ab[1], ab[2], ab[3]);
      *(float4*)&sm[OFF_ACT + p1 * WS + n0 + 4] = make_float4(ab[4], ab[5], ab[6], ab[7]);
    }
    __syncthreads();                                   // bar 3

    // ---- D: diffusion layer 2 + head + cotangent seed ----
    float z2a[8], z2b[8];
    fwd_mm(sm, OFF_WG2, OFF_GB2, p0, p1, n0, z2a, z2b);
    float g0a, g1a, g0b, g1b;        // clipped vol
    float cr0a, cr1a, cr0b, cr1b;    // c_raw = v*g*sigmoid(raw)*mask
    {
      float pr0a = 0, pr1a = 0, pr0b = 0, pr1b = 0;
      #pragma unroll
      for (int j = 0; j < 8; ++j){
        int n = n0 + j;
        float s_a = fsilu(z2a[j]), s_b = fsilu(z2b[j]);
        float w0 = sm[OFF_GW3T + n], w1 = sm[OFF_GW3T + H + n];
        pr0a += s_a * w0; pr1a += s_a * w1;
        pr0b += s_b * w0; pr1b += s_b * w1;
      }
      red16x4(pr0a, pr1a, pr0b, pr1b);
      float r0a = pr0a + sm[OFF_GB3], r1a = pr1a + sm[OFF_GB3 + 1];
      float r0b = pr0b + sm[OFF_GB3], r1b = pr1b + sm[OFF_GB3 + 1];
      auto vol = [](float raw, float& g, float& cs){
        float sp = fsoftplus(raw);
        g = fminf(fmaxf(sp, 1e-4f), 5.0f);
        float mask = (sp > 1e-4f && sp < 5.0f) ? 1.0f : 0.0f;
        cs = g * fsig(raw) * mask;
      };
      float cs;
      vol(r0a, g0a, cs); cr0a = v00 * cs;
      vol(r1a, g1a, cs); cr1a = v01 * cs;
      vol(r0b, g0b, cs); cr0b = v10 * cs;
      vol(r1b, g1b, cs); cr1b = v11 * cs;
    }
    // c2 = (c_raw @ gw3^T) * silu'(z2)
    float c2a[8], c2b[8];
    #pragma unroll
    for (int j = 0; j < 8; ++j){
      int n = n0 + j;
      float w0 = sm[OFF_GW3T + n], w1 = sm[OFF_GW3T + H + n];
      c2a[j] = (cr0a * w0 + cr1a * w1) * fsilud(z2a[j]);
      c2b[j] = (cr0b * w0 + cr1b * w1) * fsilud(z2b[j]);
    }
    __syncthreads();                                   // bar 4 (act reads done)
    *(float4*)&sm[OFF_ACT + p0 * WS + n0]     = make_float4(c2a[0], c2a[1], c2a[2], c2a[3]);
    *(float4*)&sm[OFF_ACT + p0 * WS + n0 + 4] = make_float4(c2a[4], c2a[5], c2a[6], c2a[7]);
    *(float4*)&sm[OFF_ACT + p1 * WS + n0]     = make_float4(c2b[0], c2b[1], c2b[2], c2b[3]);
    *(float4*)&sm[OFF_ACT + p1 * WS + n0 + 4] = make_float4(c2b[4], c2b[5], c2b[6], c2b[7]);
    __syncthreads();                                   // bar 5

    // ---- E: backward c1 = (c2 @ gw2^T) * silu'(z1); corr = c1 @ gw1^T ----
    float corr0a, corr1a, corr0b, corr1b;
    {
      float c1pa[8] = {0,0,0,0,0,0,0,0}, c1pb[8] = {0,0,0,0,0,0,0,0};
      const float* wg = sm + OFF_WG2;
      const float* ca = sm + OFF_ACT + p0 * WS;
      const float* cb = sm + OFF_ACT + p1 * WS;
      #pragma unroll 2
      for (int i = 0; i < 32; ++i){
        int n = ((i + (ng << 1)) & 31) << 2;           // ng-staggered to spread banks
        float4 va = *(const float4*)(ca + n);
        float4 vb = *(const float4*)(cb + n);
        #pragma unroll
        for (int j = 0; j < 8; ++j){
          float4 w = *(const float4*)(wg + (n0 + j) * WS + n);
          c1pa[j] += va.x * w.x + va.y * w.y + va.z * w.z + va.w * w.w;
          c1pb[j] += vb.x * w.x + vb.y * w.y + vb.z * w.z + vb.w * w.w;
        }
      }
      float pc0a = 0, pc1a = 0, pc0b = 0, pc1b = 0;
      #pragma unroll
      for (int j = 0; j < 8; ++j){
        int n = n0 + j;
        float c1aj = c1pa[j] * fsilud(z1a[j]);
        float c1bj = c1pb[j] * fsilud(z1b[j]);
        float w0 = sm[OFF_GW1 + n], w1 = sm[OFF_GW1 + H + n];
        pc0a += c1aj * w0; pc1a += c1aj * w1;
        pc0b += c1bj * w0; pc1b += c1bj * w1;
      }
      red16x4(pc0a, pc1a, pc0b, pc1b);
      corr0a = pc0a; corr1a = pc1a; corr0b = pc0b; corr1b = pc1b;
    }

    // ---- F: Milstein update + output ----
    float na0 = ya0 + f0a * dt + g0a * dw00 + corr0a;
    float na1 = ya1 + f1a * dt + g1a * dw01 + corr1a;
    float nb0 = yb0 + f0b * dt + g0b * dw10 + corr0b;
    float nb1 = yb1 + f1b * dt + g1b * dw11 + corr1b;
    if (ng == 0){
      sm[OFF_Y + p0 * 2] = na0; sm[OFF_Y + p0 * 2 + 1] = na1;
      sm[OFF_Y + p1 * 2] = nb0; sm[OFF_Y + p1 * 2 + 1] = nb1;
      size_t r0 = (size_t)(gpb + p0) * TLEN + (t + 1);
      size_t r1 = (size_t)(gpb + p1) * TLEN + (t + 1);
      if (isbf){
        ((unsigned*)out)[r0] = (unsigned)f2bf(na0) | ((unsigned)f2bf(na1) << 16);
        ((unsigned*)out)[r1] = (unsigned)f2bf(nb0) | ((unsigned)f2bf(nb1) << 16);
      } else {
        ((float2*)out)[r0] = make_float2(na0, na1);
        ((float2*)out)[r1] = make_float2(nb0, nb1);
      }
    }
    __syncthreads();                                   // bar 6
  }
}

extern "C" void kernel_launch(void* const* d_in, const int* in_sizes, int n_in,
                              void* d_out, int out_size, void* d_ws, size_t ws_size,
                              hipStream_t stream)
{
  (void)in_sizes; (void)n_in; (void)out_size; (void)d_ws; (void)ws_size;
  hipFuncSetAttribute((const void*)GeneratorSDE_kernel,
                      hipFuncAttributeMaxDynamicSharedMemorySize, SMEM_BYTES);
  GeneratorSDE_kernel<<<dim3(NPATH / BP), dim3(NTHR), SMEM_BYTES, stream>>>(
      d_in[0], d_in[1], d_in[2],
      d_in[3], d_in[4], d_in[5], d_in[6], d_in[7], d_in[8],
      d_in[9], d_in[10], d_in[11], d_in[12], d_in[13], d_in[14],
      d_out);
}

// Round 2
// 12635.150 us; speedup vs baseline: 1.0647x; 1.0647x over previous
//
#include <hip/hip_runtime.h>
#include <math.h>

#define H      128
#define NPATH  8192
#define TLEN   512
#define BP     32            // paths per block (8 waves x 4 paths)
#define NTHR   512

// LDS layout (float offsets). Weights XOR-swizzled, no padding.
#define OFF_WF2   0                         // fw2 [128][128] swizzled
#define OFF_WG2   (OFF_WF2 + H*H)           // gw2 [128][128] swizzled
#define OFF_ACT   (OFF_WG2 + H*H)           // actT [128 neurons][32 paths] swizzled
#define OFF_FW1   (OFF_ACT + H*32)          // fw1 [3][128]
#define OFF_FB1   (OFF_FW1 + 3*H)
#define OFF_FB2   (OFF_FB1 + H)
#define OFF_FW3T  (OFF_FB2 + H)             // fw3^T [2][128]
#define OFF_GW1   (OFF_FW3T + 2*H)          // gw1 [2][128]
#define OFF_GB1   (OFF_GW1 + 2*H)
#define OFF_GB2   (OFF_GB1 + H)
#define OFF_GW3T  (OFF_GB2 + H)             // gw3^T [2][128]
#define OFF_FB3   (OFF_GW3T + 2*H)          // [2]
#define OFF_GB3   (OFF_FB3 + 2)             // [2]
#define SMEM_FLOATS (OFF_GB3 + 2)
#define SMEM_BYTES  (SMEM_FLOATS * 4)       // 154128 B < 160 KiB

__device__ __forceinline__ float bf2f(unsigned v){         // v = raw 16-bit in low half
  return __uint_as_float(v << 16);
}
__device__ __forceinline__ unsigned short f2bf(float f){   // round-to-nearest-even
  unsigned u = __float_as_uint(f);
  return (unsigned short)((u + 0x7fffu + ((u >> 16) & 1u)) >> 16);
}
__device__ __forceinline__ float ldany(const void* p, long long i, bool isbf){
  return isbf ? bf2f(((const unsigned short*)p)[i]) : ((const float*)p)[i];
}
__device__ __forceinline__ float fsig(float x){
  return __builtin_amdgcn_rcpf(1.0f + __expf(-x));
}
__device__ __forceinline__ float fsilu(float x){ return x * fsig(x); }
__device__ __forceinline__ float fsilud(float x){
  float s = fsig(x); return s * (1.0f + x * (1.0f - s));
}
__device__ __forceinline__ float fsoftplus(float x){
  if (x > 15.0f) return x;
  return __logf(1.0f + __expf(x));
}
// full-wave (64-lane) butterfly sum of 8 values
__device__ __forceinline__ void red64x8(float v[8]){
  #pragma unroll
  for (int m = 1; m < 64; m <<= 1){
    #pragma unroll
    for (int i = 0; i < 8; ++i) v[i] += __shfl_xor(v[i], m, 64);
  }
}
// load 8 consecutive elements (2 per 4 paths) of dW, converted to fp32
__device__ __forceinline__ void ld_dw8(const void* dW, long long elem, bool isbf, float o[8]){
  if (isbf){
    uint4 q = *(const uint4*)((const unsigned short*)dW + elem);
    unsigned r[4] = {q.x, q.y, q.z, q.w};
    #pragma unroll
    for (int i = 0; i < 4; ++i){
      o[2*i]   = bf2f(r[i] & 0xffffu);
      o[2*i+1] = bf2f(r[i] >> 16);
    }
  } else {
    const float4* p = (const float4*)((const float*)dW + elem);
    float4 a = p[0], b = p[1];
    o[0]=a.x; o[1]=a.y; o[2]=a.z; o[3]=a.w; o[4]=b.x; o[5]=b.y; o[6]=b.z; o[7]=b.w;
  }
}

// forward 128x128 matmul slice: z[j][p] = bias[n0+j] + sum_k act[k][p] * W[k][n0+j]
__device__ __forceinline__ void fwd128(const float* sm, int woff, int boff,
                                       int ng2, int ngo, int wid, int n0,
                                       float za[4], float zb[4])
{
  float b0 = sm[boff + n0], b1 = sm[boff + n0 + 1];
  #pragma unroll
  for (int p = 0; p < 4; ++p){ za[p] = b0; zb[p] = b1; }
  #pragma unroll 4
  for (int k = 0; k < H; ++k){
    float4 a  = *(const float4*)&sm[OFF_ACT + k*32 + ((wid ^ ((k>>1)&7)) << 2)];
    float2 wv = *(const float2*)&sm[woff + k*H + (((ng2 ^ ((k>>2)&31)) << 2) | ngo)];
    za[0] += a.x*wv.x; za[1] += a.y*wv.x; za[2] += a.z*wv.x; za[3] += a.w*wv.x;
    zb[0] += a.x*wv.y; zb[1] += a.y*wv.y; zb[2] += a.z*wv.y; zb[3] += a.w*wv.y;
  }
}

__global__ __launch_bounds__(NTHR, 1)
void GeneratorSDE_kernel(const void* __restrict__ y0, const void* __restrict__ ts,
                         const void* __restrict__ dW,
                         const void* __restrict__ fw1, const void* __restrict__ fb1,
                         const void* __restrict__ fw2, const void* __restrict__ fb2,
                         const void* __restrict__ fw3, const void* __restrict__ fb3,
                         const void* __restrict__ gw1, const void* __restrict__ gb1,
                         const void* __restrict__ gw2, const void* __restrict__ gb2,
                         const void* __restrict__ gw3, const void* __restrict__ gb3,
                         void* __restrict__ out)
{
  extern __shared__ float sm[];
  const int tid = threadIdx.x;
  const int ng  = tid & 63;        // lane: owns neurons n0, n0+1
  const int wid = tid >> 6;        // wave: owns paths 4*wid .. 4*wid+3
  const int ng2 = ng >> 1;
  const int ngo = (ng & 1) * 2;
  const int n0  = ng * 2;
  const int gp0 = blockIdx.x * BP + wid * 4;   // first global path of this wave

  // dtype probe: fp32 ts[1] == 1.0f bit pattern; bf16 packs (2.0,3.0) there.
  const bool isbf = (((const unsigned*)ts)[1] != 0x3f800000u);

  // ---- stage weights into LDS (fp32, XOR-swizzled) ----
  for (int e = tid; e < H * H; e += NTHR){
    int k = e >> 7, n = e & 127;
    int dst = k*H + ((((n >> 2) ^ ((k >> 2) & 31)) << 2) | (n & 3));
    sm[OFF_WF2 + dst] = ldany(fw2, e, isbf);
    sm[OFF_WG2 + dst] = ldany(gw2, e, isbf);
  }
  for (int e = tid; e < 3 * H; e += NTHR) sm[OFF_FW1 + e] = ldany(fw1, e, isbf);
  for (int e = tid; e < 2 * H; e += NTHR) sm[OFF_GW1 + e] = ldany(gw1, e, isbf);
  for (int e = tid; e < H; e += NTHR){
    sm[OFF_FB1 + e] = ldany(fb1, e, isbf);
    sm[OFF_FB2 + e] = ldany(fb2, e, isbf);
    sm[OFF_GB1 + e] = ldany(gb1, e, isbf);
    sm[OFF_GB2 + e] = ldany(gb2, e, isbf);
    sm[OFF_FW3T + e]     = ldany(fw3, 2*e + 0, isbf);
    sm[OFF_FW3T + H + e] = ldany(fw3, 2*e + 1, isbf);
    sm[OFF_GW3T + e]     = ldany(gw3, 2*e + 0, isbf);
    sm[OFF_GW3T + H + e] = ldany(gw3, 2*e + 1, isbf);
  }
  if (tid < 2){ sm[OFF_FB3 + tid] = ldany(fb3, tid, isbf);
                sm[OFF_GB3 + tid] = ldany(gb3, tid, isbf); }

  // ---- y for this wave's 4 paths: registers, redundant across lanes ----
  float y[4][2];
  #pragma unroll
  for (int p = 0; p < 4; ++p){
    y[p][0] = ldany(y0, (long long)(gp0 + p)*2 + 0, isbf);
    y[p][1] = ldany(y0, (long long)(gp0 + p)*2 + 1, isbf);
  }
  // t=0 output row (lanes 0..3 of each wave store one path each)
  if (ng < 4){
    size_t r = (size_t)(gp0 + ng) * TLEN;
    if (isbf) ((unsigned*)out)[r] = (unsigned)f2bf(y[ng][0]) | ((unsigned)f2bf(y[ng][1]) << 16);
    else      ((float2*)out)[r] = make_float2(y[ng][0], y[ng][1]);
  }
  __syncthreads();   // the ONLY block-wide barrier: weights ready

  const int cA = (wid ^ (ng & 7)) << 2;   // act chunk for this thread's rows n0,n0+1

  // dW prefetch (one step ahead)
  float cur[8];
  ld_dw8(dW, (long long)gp0 * 2, isbf, cur);

  for (int t = 0; t < TLEN - 1; ++t){
    float nxt[8];
    int tn = (t + 1 <= TLEN - 2) ? t + 1 : TLEN - 2;
    ld_dw8(dW, ((long long)tn * NPATH + gp0) * 2, isbf, nxt);   // issue early

    float tc = ldany(ts, t, isbf), tq = ldany(ts, t + 1, isbf);
    float dt = tq - tc;
    float sq = sqrtf(dt);
    float dwv[4][2], vv[4][2];
    #pragma unroll
    for (int p = 0; p < 4; ++p){
      #pragma unroll
      for (int d = 0; d < 2; ++d){
        float w = cur[p*2 + d] * sq;
        dwv[p][d] = w;
        vv[p][d]  = 0.5f * (w * w - dt);
      }
    }

    // ---- A: drift layer 1 -> actT ----
    {
      float ha[2][4];
      #pragma unroll
      for (int j = 0; j < 2; ++j){
        int n = n0 + j;
        float w0 = sm[OFF_FW1 + n], w1 = sm[OFF_FW1 + H + n], w2 = sm[OFF_FW1 + 2*H + n];
        float b  = sm[OFF_FB1 + n];
        #pragma unroll
        for (int p = 0; p < 4; ++p)
          ha[j][p] = fsilu(b + y[p][0]*w0 + y[p][1]*w1 + (y[p][0]-y[p][1])*w2);
      }
      *(float4*)&sm[OFF_ACT + n0*32 + cA]       = make_float4(ha[0][0], ha[0][1], ha[0][2], ha[0][3]);
      *(float4*)&sm[OFF_ACT + (n0+1)*32 + cA]   = make_float4(ha[1][0], ha[1][1], ha[1][2], ha[1][3]);
    }

    // ---- B: drift layer 2 + head ----
    float ff[8];   // f[d][p] at ff[d*4+p]
    {
      float za[4], zb[4];
      fwd128(sm, OFF_WF2, OFF_FB2, ng2, ngo, wid, n0, za, zb);
      float w30 = sm[OFF_FW3T + n0],     w31 = sm[OFF_FW3T + n0 + 1];
      float w40 = sm[OFF_FW3T + H + n0], w41 = sm[OFF_FW3T + H + n0 + 1];
      #pragma unroll
      for (int p = 0; p < 4; ++p){
        float s0 = fsilu(za[p]), s1 = fsilu(zb[p]);
        ff[p]     = s0*w30 + s1*w31;
        ff[4 + p] = s0*w40 + s1*w41;
      }
      red64x8(ff);
      float b0 = sm[OFF_FB3], b1 = sm[OFF_FB3 + 1];
      #pragma unroll
      for (int p = 0; p < 4; ++p){ ff[p] += b0; ff[4+p] += b1; }
    }

    // ---- C: diffusion layer 1 -> actT (keep z1 in regs) ----
    float z1a[4], z1b[4];
    {
      float hc[2][4];
      #pragma unroll
      for (int j = 0; j < 2; ++j){
        int n = n0 + j;
        float w0 = sm[OFF_GW1 + n], w1 = sm[OFF_GW1 + H + n], b = sm[OFF_GB1 + n];
        #pragma unroll
        for (int p = 0; p < 4; ++p){
          float z = b + y[p][0]*w0 + y[p][1]*w1;
          if (j == 0) z1a[p] = z; else z1b[p] = z;
          hc[j][p] = fsilu(z);
        }
      }
      *(float4*)&sm[OFF_ACT + n0*32 + cA]     = make_float4(hc[0][0], hc[0][1], hc[0][2], hc[0][3]);
      *(float4*)&sm[OFF_ACT + (n0+1)*32 + cA] = make_float4(hc[1][0], hc[1][1], hc[1][2], hc[1][3]);
    }

    // ---- D: diffusion layer 2 + head + cotangent seed -> actT ----
    float gg[8];   // clipped vol g[d][p] at gg[d*4+p]
    {
      float z2a[4], z2b[4];
      fwd128(sm, OFF_WG2, OFF_GB2, ng2, ngo, wid, n0, z2a, z2b);
      float w30 = sm[OFF_GW3T + n0],     w31 = sm[OFF_GW3T + n0 + 1];
      float w40 = sm[OFF_GW3T + H + n0], w41 = sm[OFF_GW3T + H + n0 + 1];
      float pr[8];
      #pragma unroll
      for (int p = 0; p < 4; ++p){
        float s0 = fsilu(z2a[p]), s1 = fsilu(z2b[p]);
        pr[p]     = s0*w30 + s1*w31;
        pr[4 + p] = s0*w40 + s1*w41;
      }
      red64x8(pr);
      float b0 = sm[OFF_GB3], b1 = sm[OFF_GB3 + 1];
      float cr[2][4];
      #pragma unroll
      for (int d = 0; d < 2; ++d){
        #pragma unroll
        for (int p = 0; p < 4; ++p){
          float raw = pr[d*4 + p] + (d ? b1 : b0);
          float sp  = fsoftplus(raw);
          float g   = fminf(fmaxf(sp, 1e-4f), 5.0f);
          gg[d*4 + p] = g;
          float mask = (sp > 1e-4f && sp < 5.0f) ? 1.0f : 0.0f;
          cr[d][p] = vv[p][d] * (g * fsig(raw) * mask);
        }
      }
      float c2[2][4];
      #pragma unroll
      for (int j = 0; j < 2; ++j){
        float u0 = (j ? w31 : w30), u1 = (j ? w41 : w40);
        #pragma unroll
        for (int p = 0; p < 4; ++p){
          float z = (j ? z2b[p] : z2a[p]);
          c2[j][p] = (cr[0][p]*u0 + cr[1][p]*u1) * fsilud(z);
        }
      }
      *(float4*)&sm[OFF_ACT + n0*32 + cA]     = make_float4(c2[0][0], c2[0][1], c2[0][2], c2[0][3]);
      *(float4*)&sm[OFF_ACT + (n0+1)*32 + cA] = make_float4(c2[1][0], c2[1][1], c2[1][2], c2[1][3]);
    }

    // ---- E: backward through gw2 (c1 = (c2 @ gw2^T) * silu'(z1)); corr head ----
    float corr[8];   // corr[d][p] at corr[d*4+p]
    {
      float c1a[4] = {0,0,0,0}, c1b[4] = {0,0,0,0};
      const int sB = ng2;                       // (k0>>2)&31 for rows 2ng, 2ng+1
      #pragma unroll 2
      for (int c = 0; c < 32; ++c){
        int cx = (c ^ sB) << 2;
        const float* wr = &sm[OFF_WG2 + n0*H + cx];
        float4 w0 = *(const float4*)wr;          // gw2[2ng][4c..4c+3]
        float4 w1 = *(const float4*)(wr + H);    // gw2[2ng+1][...]
        int n = 4*c;
        int e0 = (wid ^ ((2*c) & 7)) << 2;
        int e1 = (wid ^ ((2*c + 1) & 7)) << 2;
        float4 a0 = *(const float4*)&sm[OFF_ACT + n*32 + e0];
        float4 a1 = *(const float4*)&sm[OFF_ACT + (n+1)*32 + e0];
        float4 a2 = *(const float4*)&sm[OFF_ACT + (n+2)*32 + e1];
        float4 a3 = *(const float4*)&sm[OFF_ACT + (n+3)*32 + e1];
        const float* f0 = (const float*)&a0; const float* f1 = (const float*)&a1;
        const float* f2 = (const float*)&a2; const float* f3 = (const float*)&a3;
        #pragma unroll
        for (int p = 0; p < 4; ++p){
          c1a[p] += f0[p]*w0.x + f1[p]*w0.y + f2[p]*w0.z + f3[p]*w0.w;
          c1b[p] += f0[p]*w1.x + f1[p]*w1.y + f2[p]*w1.z + f3[p]*w1.w;
        }
      }
      float g10 = sm[OFF_GW1 + n0],     g11 = sm[OFF_GW1 + n0 + 1];
      float g20 = sm[OFF_GW1 + H + n0], g21 = sm[OFF_GW1 + H + n0 + 1];
      #pragma unroll
      for (int p = 0; p < 4; ++p){
        float u0 = c1a[p] * fsilud(z1a[p]);
        float u1 = c1b[p] * fsilud(z1b[p]);
        corr[p]     = u0*g10 + u1*g11;
        corr[4 + p] = u0*g20 + u1*g21;
      }
      red64x8(corr);
    }

    // ---- F: Milstein update + output ----
    #pragma unroll
    for (int p = 0; p < 4; ++p){
      #pragma unroll
      for (int d = 0; d < 2; ++d)
        y[p][d] += ff[d*4 + p]*dt + gg[d*4 + p]*dwv[p][d] + corr[d*4 + p];
    }
    if (ng < 4){
      size_t r = (size_t)(gp0 + ng) * TLEN + (t + 1);
      if (isbf) ((unsigned*)out)[r] = (unsigned)f2bf(y[ng][0]) | ((unsigned)f2bf(y[ng][1]) << 16);
      else      ((float2*)out)[r] = make_float2(y[ng][0], y[ng][1]);
    }

    #pragma unroll
    for (int i = 0; i < 8; ++i) cur[i] = nxt[i];
  }
}

extern "C" void kernel_launch(void* const* d_in, const int* in_sizes, int n_in,
                              void* d_out, int out_size, void* d_ws, size_t ws_size,
                              hipStream_t stream)
{
  (void)in_sizes; (void)n_in; (void)out_size; (void)d_ws; (void)ws_size;
  hipFuncSetAttribute((const void*)GeneratorSDE_kernel,
                      hipFuncAttributeMaxDynamicSharedMemorySize, SMEM_BYTES);
  GeneratorSDE_kernel<<<dim3(NPATH / BP), dim3(NTHR), SMEM_BYTES, stream>>>(
      d_in[0], d_in[1], d_in[2],
      d_in[3], d_in[4], d_in[5], d_in[6], d_in[7], d_in[8],
      d_in[9], d_in[10], d_in[11], d_in[12], d_in[13], d_in[14],
      d_out);
}

// Round 3
// 2990.466 us; speedup vs baseline: 4.4986x; 4.2251x over previous
//
#include <hip/hip_runtime.h>
#include <math.h>

#define H      128
#define NPATH  8192
#define TLEN   512
#define BP     32            // paths per block
#define NTHR   256           // 4 waves

typedef short bf16x8 __attribute__((ext_vector_type(8)));
typedef float f32x4  __attribute__((ext_vector_type(4)));

#define MFMA(a,b,c) __builtin_amdgcn_mfma_f32_16x16x32_bf16((a),(b),(c),0,0,0)

// ---- LDS byte offsets ----
#define O_WF2T  0                    // fw2^T  [m=nout][k]  bf16 swizzled (fwd-f A)
#define O_WG2T  (O_WF2T + 32768)     // gw2^T  (fwd-g A)
#define O_WG2R  (O_WG2T + 32768)     // gw2    [m=k][n]     (bwd A)
#define O_BFH   (O_WG2R + 32768)     // B buf: h1f hi  [p][k] bf16 swizzled (reused for c2 hi)
#define O_BFL   (O_BFH + 8192)       // h1f lo (reused c2 lo)
#define O_BGH   (O_BFL + 8192)       // h1g hi
#define O_BGL   (O_BGH + 8192)       // h1g lo
#define O_PF    (O_BGL + 8192)       // f partials    [4][32][2] fp32
#define O_PRAW  (O_PF   + 1024)      // raw partials
#define O_PCORR (O_PRAW + 1024)      // corr partials
#define O_CR    (O_PCORR+ 1024)      // cr [32][2] fp32
#define O_YB    (O_CR   + 256)       // y  [32][2] fp32
#define O_TS    (O_YB   + 256)       // ts [512] fp32
#define SMEM_BYTES (O_TS + TLEN*4)   // 136704 < 160 KiB

__device__ __forceinline__ float bf2f(unsigned v){ return __uint_as_float(v << 16); }
__device__ __forceinline__ unsigned short f2bf(float f){
  unsigned u = __float_as_uint(f);
  return (unsigned short)((u + 0x7fffu + ((u >> 16) & 1u)) >> 16);
}
__device__ __forceinline__ float ldany(const void* p, long long i, bool isbf){
  return isbf ? bf2f(((const unsigned short*)p)[i]) : ((const float*)p)[i];
}
__device__ __forceinline__ unsigned short ldbf(const void* p, long long i, bool isbf){
  return isbf ? ((const unsigned short*)p)[i] : f2bf(((const float*)p)[i]);
}
__device__ __forceinline__ float fsig(float x){
  return __builtin_amdgcn_rcpf(1.0f + __expf(-x));
}
__device__ __forceinline__ float fsilu(float x){ return x * fsig(x); }
__device__ __forceinline__ float fsilud(float x){
  float s = fsig(x); return s * (1.0f + x * (1.0f - s));
}
__device__ __forceinline__ float fsoftplus(float x){
  if (x > 15.0f) return x;
  return __logf(1.0f + __expf(x));
}
__device__ __forceinline__ void split2(float x, unsigned short& hi, unsigned short& lo){
  unsigned short h = f2bf(x);
  hi = h;
  lo = f2bf(x - bf2f(h));
}
// byte offset of bf16 element (row, col) in a [R][128] chunk-swizzled buffer
__device__ __forceinline__ int physB(int row, int col){
  return (row << 8) + ((((col >> 3) ^ (row & 15)) << 4) | ((col & 7) << 1));
}
__device__ __forceinline__ bf16x8 ldfrag(const char* base, int row, int col){
  union { uint4 u; bf16x8 b; } v;
  v.u = *(const uint4*)(base + physB(row, col));
  return v.b;
}
__device__ __forceinline__ void st8(char* base, int row, int col, const unsigned short h[8]){
  uint4 u = make_uint4((unsigned)h[0] | ((unsigned)h[1] << 16),
                       (unsigned)h[2] | ((unsigned)h[3] << 16),
                       (unsigned)h[4] | ((unsigned)h[5] << 16),
                       (unsigned)h[6] | ((unsigned)h[7] << 16));
  *(uint4*)(base + physB(row, col)) = u;
}
__device__ __forceinline__ void st4(char* base, int row, int col, const unsigned short h[4]){
  uint2 u = make_uint2((unsigned)h[0] | ((unsigned)h[1] << 16),
                       (unsigned)h[2] | ((unsigned)h[3] << 16));
  *(uint2*)(base + physB(row, col)) = u;
}

__global__ __launch_bounds__(NTHR, 1)
void GeneratorSDE_kernel(const void* __restrict__ y0, const void* __restrict__ ts,
                         const void* __restrict__ dW,
                         const void* __restrict__ fw1, const void* __restrict__ fb1,
                         const void* __restrict__ fw2, const void* __restrict__ fb2,
                         const void* __restrict__ fw3, const void* __restrict__ fb3,
                         const void* __restrict__ gw1, const void* __restrict__ gb1,
                         const void* __restrict__ gw2, const void* __restrict__ gb2,
                         const void* __restrict__ gw3, const void* __restrict__ gb3,
                         void* __restrict__ out)
{
  extern __shared__ char sm[];
  const int tid  = threadIdx.x;
  const int lane = tid & 63;
  const int w    = tid >> 6;       // wave 0..3, owns M-tiles {2w,2w+1}, paths 8w..8w+7
  const int m16  = lane & 15;
  const int q    = lane >> 4;
  const int gpb  = blockIdx.x * BP;

  const bool isbf = (((const unsigned*)ts)[1] != 0x3f800000u);

  // ---------- init: stage weights into LDS (bf16, chunk-swizzled) ----------
  for (int e = tid; e < H * H; e += NTHR){
    int k = e >> 7, n = e & 127;
    unsigned short fv = ldbf(fw2, e, isbf);
    unsigned short gv = ldbf(gw2, e, isbf);
    *(unsigned short*)(sm + O_WF2T + physB(n, k)) = fv;
    *(unsigned short*)(sm + O_WG2T + physB(n, k)) = gv;
    *(unsigned short*)(sm + O_WG2R + physB(k, n)) = gv;
  }
  for (int e = tid; e < TLEN; e += NTHR)
    ((float*)(sm + O_TS))[e] = ldany(ts, e, isbf);

  // ---------- per-lane register preloads ----------
  // head rows owned by this lane: nrow(i) = 32w + (i>>2)*16 + q*4 + (i&3)
  float w3f0[8], w3f1[8], w3g0[8], w3g1[8], gw1b0[8], gw1b1[8], gb1b[8];
  #pragma unroll
  for (int i = 0; i < 8; ++i){
    int nr = 32*w + ((i >> 2) << 4) + (q << 2) + (i & 3);
    w3f0[i]  = ldany(fw3, 2*nr + 0, isbf);
    w3f1[i]  = ldany(fw3, 2*nr + 1, isbf);
    w3g0[i]  = ldany(gw3, 2*nr + 0, isbf);
    w3g1[i]  = ldany(gw3, 2*nr + 1, isbf);
    gw1b0[i] = ldany(gw1, nr,       isbf);
    gw1b1[i] = ldany(gw1, H + nr,   isbf);
    gb1b[i]  = ldany(gb1, nr,       isbf);
  }
  // layer-1 weights for this lane's path/k-slice: path p1, k = (lane&7)*16 + kk
  const int p1 = 8*w + (lane >> 3);
  const int k16 = (lane & 7) << 4;
  float fw1r0[16], fw1r1[16], fw1r2[16], fb1r[16], gw1r0[16], gw1r1[16], gb1r[16];
  #pragma unroll
  for (int kk = 0; kk < 16; ++kk){
    int k = k16 + kk;
    fw1r0[kk] = ldany(fw1, k,       isbf);
    fw1r1[kk] = ldany(fw1, H + k,   isbf);
    fw1r2[kk] = ldany(fw1, 2*H + k, isbf);
    fb1r[kk]  = ldany(fb1, k,       isbf);
    gw1r0[kk] = ldany(gw1, k,       isbf);
    gw1r1[kk] = ldany(gw1, H + k,   isbf);
    gb1r[kk]  = ldany(gb1, k,       isbf);
  }
  const float fb3r0 = ldany(fb3, 0, isbf), fb3r1 = ldany(fb3, 1, isbf);
  const float gb3r0 = ldany(gb3, 0, isbf), gb3r1 = ldany(gb3, 1, isbf);

  // ---------- y0 -> LDS, t=0 output, dW prefetch ----------
  float2 dwcur = make_float2(0.f, 0.f);
  if (lane < 8){
    int p  = 8*w + lane;
    int gp = gpb + p;
    float a = ldany(y0, (long long)gp*2 + 0, isbf);
    float b = ldany(y0, (long long)gp*2 + 1, isbf);
    *(float2*)(sm + O_YB + p*8) = make_float2(a, b);
    size_t r = (size_t)gp * TLEN;
    if (isbf) ((unsigned*)out)[r] = (unsigned)f2bf(a) | ((unsigned)f2bf(b) << 16);
    else      ((float2*)out)[r]   = make_float2(a, b);
    long long e = (long long)gp * 2;                     // t = 0
    if (isbf){ unsigned u = *(const unsigned*)((const unsigned short*)dW + e);
               dwcur = make_float2(bf2f(u & 0xffffu), bf2f(u >> 16)); }
    else       dwcur = *(const float2*)((const float*)dW + e);
  }
  __syncthreads();

  const float* TSf = (const float*)(sm + O_TS);

  for (int t = 0; t < TLEN - 1; ++t){
    float dt = TSf[t+1] - TSf[t];
    float sqdt = sqrtf(dt);

    // ---- S0: layer 1 (drift + diffusion), split hi/lo -> B buffers ----
    float2 dwnext = make_float2(0.f, 0.f);
    if (lane < 8){
      int tn = (t + 1 <= TLEN - 2) ? t + 1 : TLEN - 2;
      long long e = ((long long)tn * NPATH + (gpb + 8*w + lane)) * 2;
      if (isbf){ unsigned u = *(const unsigned*)((const unsigned short*)dW + e);
                 dwnext = make_float2(bf2f(u & 0xffffu), bf2f(u >> 16)); }
      else       dwnext = *(const float2*)((const float*)dW + e);
    }
    {
      float2 yp = *(const float2*)(sm + O_YB + p1*8);
      float ya = yp.x, yb = yp.y, ysp = ya - yb;
      unsigned short fh[16], fl[16], gh[16], gl[16];
      #pragma unroll
      for (int kk = 0; kk < 16; ++kk){
        float hf = fsilu(fb1r[kk] + ya*fw1r0[kk] + yb*fw1r1[kk] + ysp*fw1r2[kk]);
        float hg = fsilu(gb1r[kk] + ya*gw1r0[kk] + yb*gw1r1[kk]);
        split2(hf, fh[kk], fl[kk]);
        split2(hg, gh[kk], gl[kk]);
      }
      st8(sm + O_BFH, p1, k16,     fh);  st8(sm + O_BFH, p1, k16 + 8, fh + 8);
      st8(sm + O_BFL, p1, k16,     fl);  st8(sm + O_BFL, p1, k16 + 8, fl + 8);
      st8(sm + O_BGH, p1, k16,     gh);  st8(sm + O_BGH, p1, k16 + 8, gh + 8);
      st8(sm + O_BGL, p1, k16,     gl);  st8(sm + O_BGL, p1, k16 + 8, gl + 8);
    }
    __syncthreads();                                     // A

    // ---- S1: fwd MFMAs (f and g) + head partials ----
    f32x4 accg[2][2];
    {
      f32x4 accf[2][2];
      #pragma unroll
      for (int mi = 0; mi < 2; ++mi)
        #pragma unroll
        for (int nt = 0; nt < 2; ++nt){ accf[mi][nt] = (f32x4)0.f; accg[mi][nt] = (f32x4)0.f; }
      #pragma unroll
      for (int kt = 0; kt < 4; ++kt){
        int colk = kt*32 + q*8;
        bf16x8 af0 = ldfrag(sm + O_WF2T, 32*w + m16,      colk);
        bf16x8 af1 = ldfrag(sm + O_WF2T, 32*w + 16 + m16, colk);
        bf16x8 b0h = ldfrag(sm + O_BFH, m16,      colk);
        bf16x8 b1h = ldfrag(sm + O_BFH, 16 + m16, colk);
        bf16x8 b0l = ldfrag(sm + O_BFL, m16,      colk);
        bf16x8 b1l = ldfrag(sm + O_BFL, 16 + m16, colk);
        accf[0][0] = MFMA(af0, b0l, accf[0][0]); accf[0][0] = MFMA(af0, b0h, accf[0][0]);
        accf[0][1] = MFMA(af0, b1l, accf[0][1]); accf[0][1] = MFMA(af0, b1h, accf[0][1]);
        accf[1][0] = MFMA(af1, b0l, accf[1][0]); accf[1][0] = MFMA(af1, b0h, accf[1][0]);
        accf[1][1] = MFMA(af1, b1l, accf[1][1]); accf[1][1] = MFMA(af1, b1h, accf[1][1]);
        bf16x8 ag0 = ldfrag(sm + O_WG2T, 32*w + m16,      colk);
        bf16x8 ag1 = ldfrag(sm + O_WG2T, 32*w + 16 + m16, colk);
        bf16x8 c0h = ldfrag(sm + O_BGH, m16,      colk);
        bf16x8 c1h = ldfrag(sm + O_BGH, 16 + m16, colk);
        bf16x8 c0l = ldfrag(sm + O_BGL, m16,      colk);
        bf16x8 c1l = ldfrag(sm + O_BGL, 16 + m16, colk);
        accg[0][0] = MFMA(ag0, c0l, accg[0][0]); accg[0][0] = MFMA(ag0, c0h, accg[0][0]);
        accg[0][1] = MFMA(ag0, c1l, accg[0][1]); accg[0][1] = MFMA(ag0, c1h, accg[0][1]);
        accg[1][0] = MFMA(ag1, c0l, accg[1][0]); accg[1][0] = MFMA(ag1, c0h, accg[1][0]);
        accg[1][1] = MFMA(ag1, c1l, accg[1][1]); accg[1][1] = MFMA(ag1, c1h, accg[1][1]);
      }
      // heads: z2 has bias fb2/gb2 missing -> add via bias rows? No: biases!
      // accf = W2^T h1 ; need + fb2 before silu. Bias along neuron rows (this lane's rows).
      float pf[2][2] = {{0,0},{0,0}}, pr[2][2] = {{0,0},{0,0}};
      #pragma unroll
      for (int mi = 0; mi < 2; ++mi)
        #pragma unroll
        for (int r = 0; r < 4; ++r){
          int i  = mi*4 + r;
          int nr = 32*w + (mi << 4) + (q << 2) + r;
          float bf2v = ldany(fb2, nr, isbf);   // L2-cached broadcast, cheap
          float bg2v = ldany(gb2, nr, isbf);
          #pragma unroll
          for (int nt = 0; nt < 2; ++nt){
            float vf = fsilu(accf[mi][nt][r] + bf2v);
            pf[nt][0] += vf * w3f0[i];
            pf[nt][1] += vf * w3f1[i];
            float zg = accg[mi][nt][r] + bg2v;
            accg[mi][nt][r] = zg;              // keep biased z2g for S3
            float vg = fsilu(zg);
            pr[nt][0] += vg * w3g0[i];
            pr[nt][1] += vg * w3g1[i];
          }
        }
      #pragma unroll
      for (int nt = 0; nt < 2; ++nt)
        #pragma unroll
        for (int d = 0; d < 2; ++d){
          pf[nt][d] += __shfl_xor(pf[nt][d], 16, 64);
          pf[nt][d] += __shfl_xor(pf[nt][d], 32, 64);
          pr[nt][d] += __shfl_xor(pr[nt][d], 16, 64);
          pr[nt][d] += __shfl_xor(pr[nt][d], 32, 64);
        }
      if (lane < 16){
        #pragma unroll
        for (int nt = 0; nt < 2; ++nt){
          *(float2*)(sm + O_PF   + (w*32 + nt*16 + lane)*8) = make_float2(pf[nt][0], pf[nt][1]);
          *(float2*)(sm + O_PRAW + (w*32 + nt*16 + lane)*8) = make_float2(pr[nt][0], pr[nt][1]);
        }
      }
    }
    __syncthreads();                                     // B

    // ---- S2: combine raw head -> g, cr (lanes 0..7 of each wave) ----
    float g0 = 0.f, g1 = 0.f, dw0 = 0.f, dw1 = 0.f;
    if (lane < 8){
      int p = 8*w + lane;
      float raw0 = gb3r0, raw1 = gb3r1;
      #pragma unroll
      for (int w2 = 0; w2 < 4; ++w2){
        float2 prv = *(const float2*)(sm + O_PRAW + (w2*32 + p)*8);
        raw0 += prv.x; raw1 += prv.y;
      }
      dw0 = dwcur.x * sqdt; dw1 = dwcur.y * sqdt;
      float vv0 = 0.5f*(dw0*dw0 - dt), vv1 = 0.5f*(dw1*dw1 - dt);
      float sp0 = fsoftplus(raw0), sp1 = fsoftplus(raw1);
      g0 = fminf(fmaxf(sp0, 1e-4f), 5.0f);
      g1 = fminf(fmaxf(sp1, 1e-4f), 5.0f);
      float m0 = (sp0 > 1e-4f && sp0 < 5.0f) ? 1.0f : 0.0f;
      float m1 = (sp1 > 1e-4f && sp1 < 5.0f) ? 1.0f : 0.0f;
      float cr0 = vv0 * (g0 * fsig(raw0) * m0);
      float cr1 = vv1 * (g1 * fsig(raw1) * m1);
      *(float2*)(sm + O_CR + p*8) = make_float2(cr0, cr1);
    }
    __syncthreads();                                     // C

    // ---- S3: cotangent seed c2 -> B buffers (reuse BFH/BFL) ----
    float2 ynt[2];
    {
      float2 crv[2];
      #pragma unroll
      for (int nt = 0; nt < 2; ++nt){
        crv[nt] = *(const float2*)(sm + O_CR + (nt*16 + m16)*8);
        ynt[nt] = *(const float2*)(sm + O_YB + (nt*16 + m16)*8);
      }
      #pragma unroll
      for (int mi = 0; mi < 2; ++mi)
        #pragma unroll
        for (int nt = 0; nt < 2; ++nt){
          unsigned short hi[4], lo[4];
          #pragma unroll
          for (int r = 0; r < 4; ++r){
            int i = mi*4 + r;
            float c2 = (crv[nt].x * w3g0[i] + crv[nt].y * w3g1[i]) * fsilud(accg[mi][nt][r]);
            split2(c2, hi[r], lo[r]);
          }
          int rowp = nt*16 + m16;
          int coln = (2*w + mi)*16 + q*4;
          st4(sm + O_BFH, rowp, coln, hi);
          st4(sm + O_BFL, rowp, coln, lo);
        }
    }
    __syncthreads();                                     // D

    // ---- S4: backward MFMA (c1 = gw2 @ c2) + corr head partials ----
    {
      f32x4 accc[2][2];
      #pragma unroll
      for (int mi = 0; mi < 2; ++mi)
        #pragma unroll
        for (int nt = 0; nt < 2; ++nt) accc[mi][nt] = (f32x4)0.f;
      #pragma unroll
      for (int kt = 0; kt < 4; ++kt){
        int colk = kt*32 + q*8;
        bf16x8 a0 = ldfrag(sm + O_WG2R, 32*w + m16,      colk);
        bf16x8 a1 = ldfrag(sm + O_WG2R, 32*w + 16 + m16, colk);
        bf16x8 b0h = ldfrag(sm + O_BFH, m16,      colk);
        bf16x8 b1h = ldfrag(sm + O_BFH, 16 + m16, colk);
        bf16x8 b0l = ldfrag(sm + O_BFL, m16,      colk);
        bf16x8 b1l = ldfrag(sm + O_BFL, 16 + m16, colk);
        accc[0][0] = MFMA(a0, b0l, accc[0][0]); accc[0][0] = MFMA(a0, b0h, accc[0][0]);
        accc[0][1] = MFMA(a0, b1l, accc[0][1]); accc[0][1] = MFMA(a0, b1h, accc[0][1]);
        accc[1][0] = MFMA(a1, b0l, accc[1][0]); accc[1][0] = MFMA(a1, b0h, accc[1][0]);
        accc[1][1] = MFMA(a1, b1l, accc[1][1]); accc[1][1] = MFMA(a1, b1h, accc[1][1]);
      }
      float pc[2][2] = {{0,0},{0,0}};
      #pragma unroll
      for (int nt = 0; nt < 2; ++nt){
        float y0p = ynt[nt].x, y1p = ynt[nt].y;
        #pragma unroll
        for (int mi = 0; mi < 2; ++mi)
          #pragma unroll
          for (int r = 0; r < 4; ++r){
            int i = mi*4 + r;
            float z1 = gb1b[i] + y0p*gw1b0[i] + y1p*gw1b1[i];
            float u  = accc[mi][nt][r] * fsilud(z1);
            pc[nt][0] += u * gw1b0[i];
            pc[nt][1] += u * gw1b1[i];
          }
      }
      #pragma unroll
      for (int nt = 0; nt < 2; ++nt)
        #pragma unroll
        for (int d = 0; d < 2; ++d){
          pc[nt][d] += __shfl_xor(pc[nt][d], 16, 64);
          pc[nt][d] += __shfl_xor(pc[nt][d], 32, 64);
        }
      if (lane < 16){
        #pragma unroll
        for (int nt = 0; nt < 2; ++nt)
          *(float2*)(sm + O_PCORR + (w*32 + nt*16 + lane)*8) = make_float2(pc[nt][0], pc[nt][1]);
      }
    }
    __syncthreads();                                     // E

    // ---- S5: Milstein update + output (lanes 0..7 of each wave) ----
    if (lane < 8){
      int p = 8*w + lane;
      float f0 = fb3r0, f1 = fb3r1, c0 = 0.f, c1 = 0.f;
      #pragma unroll
      for (int w2 = 0; w2 < 4; ++w2){
        float2 a = *(const float2*)(sm + O_PF    + (w2*32 + p)*8);
        float2 b = *(const float2*)(sm + O_PCORR + (w2*32 + p)*8);
        f0 += a.x; f1 += a.y; c0 += b.x; c1 += b.y;
      }
      float2 yv = *(const float2*)(sm + O_YB + p*8);
      float ny0 = yv.x + f0*dt + g0*dw0 + c0;
      float ny1 = yv.y + f1*dt + g1*dw1 + c1;
      *(float2*)(sm + O_YB + p*8) = make_float2(ny0, ny1);
      size_t r = (size_t)(gpb + p) * TLEN + (t + 1);
      if (isbf) ((unsigned*)out)[r] = (unsigned)f2bf(ny0) | ((unsigned)f2bf(ny1) << 16);
      else      ((float2*)out)[r]   = make_float2(ny0, ny1);
      dwcur = dwnext;
    }
    __syncthreads();                                     // F
  }
}

extern "C" void kernel_launch(void* const* d_in, const int* in_sizes, int n_in,
                              void* d_out, int out_size, void* d_ws, size_t ws_size,
                              hipStream_t stream)
{
  (void)in_sizes; (void)n_in; (void)out_size; (void)d_ws; (void)ws_size;
  hipFuncSetAttribute((const void*)GeneratorSDE_kernel,
                      hipFuncAttributeMaxDynamicSharedMemorySize, SMEM_BYTES);
  GeneratorSDE_kernel<<<dim3(NPATH / BP), dim3(NTHR), SMEM_BYTES, stream>>>(
      d_in[0], d_in[1], d_in[2],
      d_in[3], d_in[4], d_in[5], d_in[6], d_in[7], d_in[8],
      d_in[9], d_in[10], d_in[11], d_in[12], d_in[13], d_in[14],
      d_out);
}

// Round 4
// 2065.602 us; speedup vs baseline: 6.5129x; 1.4477x over previous
//
#include <hip/hip_runtime.h>
#include <math.h>

#define H      128
#define NPATH  8192
#define TLEN   512
#define BP     32            // paths per block
#define NTHR   512           // 8 waves: (wp 0..3) x (nt 0..1)

typedef short bf16x8 __attribute__((ext_vector_type(8)));
typedef float f32x4  __attribute__((ext_vector_type(4)));

#define MFMA(a,b,c) __builtin_amdgcn_mfma_f32_16x16x32_bf16((a),(b),(c),0,0,0)

// ---- LDS byte offsets ----
#define O_WF2T  0                    // fw2^T  [out][in] bf16 swizzled (fwd-f A)
#define O_WG2T  (O_WF2T + 32768)     // gw2^T  [out][in]           (fwd-g A)
#define O_WG2R  (O_WG2T + 32768)     // gw2    [in][out]           (bwd A)
#define O_BFH   (O_WG2R + 32768)     // h1f hi [32 path][128 k] bf16 swz (reused c2 hi)
#define O_BFL   (O_BFH + 8192)       // h1f lo (reused c2 lo)
#define O_BGH   (O_BFL + 8192)       // h1g hi
#define O_BGL   (O_BGH + 8192)       // h1g lo
#define O_PF    (O_BGL + 8192)       // f partials    [4 wp][32 path][2] fp32
#define O_PRAW  (O_PF   + 1024)      // raw partials
#define O_PCORR (O_PRAW + 1024)      // corr partials
#define O_TS    (O_PCORR+ 1024)      // ts [512] fp32
#define SMEM_BYTES (O_TS + TLEN*4)   // 136192 B < 160 KiB

__device__ __forceinline__ float bf2f(unsigned v){ return __uint_as_float(v << 16); }
__device__ __forceinline__ unsigned short f2bf(float f){
  unsigned u = __float_as_uint(f);
  return (unsigned short)((u + 0x7fffu + ((u >> 16) & 1u)) >> 16);
}
__device__ __forceinline__ float ldany(const void* p, long long i, bool isbf){
  return isbf ? bf2f(((const unsigned short*)p)[i]) : ((const float*)p)[i];
}
__device__ __forceinline__ unsigned short ldbf(const void* p, long long i, bool isbf){
  return isbf ? ((const unsigned short*)p)[i] : f2bf(((const float*)p)[i]);
}
__device__ __forceinline__ float fsig(float x){
  return __builtin_amdgcn_rcpf(1.0f + __expf(-x));
}
__device__ __forceinline__ float fsilu(float x){ return x * fsig(x); }
__device__ __forceinline__ float fsilud(float x){
  float s = fsig(x); return s * (1.0f + x * (1.0f - s));
}
__device__ __forceinline__ float fsoftplus(float x){
  if (x > 15.0f) return x;
  return __logf(1.0f + __expf(x));
}
__device__ __forceinline__ void split2(float x, unsigned short& hi, unsigned short& lo){
  unsigned short h = f2bf(x);
  hi = h;
  lo = f2bf(x - bf2f(h));
}
// byte offset of bf16 element (row, col) in a [R][128] chunk-swizzled buffer
__device__ __forceinline__ int physB(int row, int col){
  return (row << 8) + ((((col >> 3) ^ (row & 15)) << 4) | ((col & 7) << 1));
}
__device__ __forceinline__ bf16x8 ldfrag(const char* base, int row, int col){
  union { uint4 u; bf16x8 b; } v;
  v.u = *(const uint4*)(base + physB(row, col));
  return v.b;
}
__device__ __forceinline__ void st8(char* base, int row, int col, const unsigned short h[8]){
  uint4 u = make_uint4((unsigned)h[0] | ((unsigned)h[1] << 16),
                       (unsigned)h[2] | ((unsigned)h[3] << 16),
                       (unsigned)h[4] | ((unsigned)h[5] << 16),
                       (unsigned)h[6] | ((unsigned)h[7] << 16));
  *(uint4*)(base + physB(row, col)) = u;
}
__device__ __forceinline__ void st4(char* base, int row, int col, const unsigned short h[4]){
  uint2 u = make_uint2((unsigned)h[0] | ((unsigned)h[1] << 16),
                       (unsigned)h[2] | ((unsigned)h[3] << 16));
  *(uint2*)(base + physB(row, col)) = u;
}

__global__ __launch_bounds__(NTHR, 2)
void GeneratorSDE_kernel(const void* __restrict__ y0, const void* __restrict__ ts,
                         const void* __restrict__ dW,
                         const void* __restrict__ fw1, const void* __restrict__ fb1,
                         const void* __restrict__ fw2, const void* __restrict__ fb2,
                         const void* __restrict__ fw3, const void* __restrict__ fb3,
                         const void* __restrict__ gw1, const void* __restrict__ gb1,
                         const void* __restrict__ gw2, const void* __restrict__ gb2,
                         const void* __restrict__ gw3, const void* __restrict__ gb3,
                         void* __restrict__ out)
{
  extern __shared__ char sm[];
  const int tid  = threadIdx.x;
  const int lane = tid & 63;
  const int w    = tid >> 6;       // wave 0..7
  const int wp   = w >> 1;         // M-pair index 0..3 (rows 32*wp..32*wp+31)
  const int nt   = w & 1;          // N-tile (paths nt*16..nt*16+15)
  const int m16  = lane & 15;
  const int q    = lane >> 4;
  const int gpb  = blockIdx.x * BP;
  const int p1   = nt*16 + m16;    // this lane's path (block-local)
  const int gp   = gpb + p1;
  const int k8   = wp*32 + q*8;    // S0 k-slice (8 neurons)

  const bool isbf = (((const unsigned*)ts)[1] != 0x3f800000u);

  // ---------- stage weights into LDS (bf16, chunk-swizzled) ----------
  for (int e = tid; e < H * H; e += NTHR){
    int k = e >> 7, n = e & 127;
    unsigned short fv = ldbf(fw2, e, isbf);
    unsigned short gv = ldbf(gw2, e, isbf);
    *(unsigned short*)(sm + O_WF2T + physB(n, k)) = fv;
    *(unsigned short*)(sm + O_WG2T + physB(n, k)) = gv;
    *(unsigned short*)(sm + O_WG2R + physB(k, n)) = gv;
  }
  for (int e = tid; e < TLEN; e += NTHR)
    ((float*)(sm + O_TS))[e] = ldany(ts, e, isbf);

  // ---------- per-lane register preloads ----------
  // head rows owned by this lane: nr(i) = 32*wp + (i>>2)*16 + q*4 + (i&3)
  float w3f0[8], w3f1[8], w3g0[8], w3g1[8], gw1b0[8], gw1b1[8], gb1b[8], fb2r[8], gb2r[8];
  #pragma unroll
  for (int i = 0; i < 8; ++i){
    int nr = 32*wp + ((i >> 2) << 4) + (q << 2) + (i & 3);
    w3f0[i]  = ldany(fw3, 2*nr + 0, isbf);
    w3f1[i]  = ldany(fw3, 2*nr + 1, isbf);
    w3g0[i]  = ldany(gw3, 2*nr + 0, isbf);
    w3g1[i]  = ldany(gw3, 2*nr + 1, isbf);
    gw1b0[i] = ldany(gw1, nr,       isbf);
    gw1b1[i] = ldany(gw1, H + nr,   isbf);
    gb1b[i]  = ldany(gb1, nr,       isbf);
    fb2r[i]  = ldany(fb2, nr,       isbf);
    gb2r[i]  = ldany(gb2, nr,       isbf);
  }
  // S0 layer-1 slices: path p1, k = k8 + kk (8 neurons)
  float fw1r0[8], fw1r1[8], fw1r2[8], fb1r[8], gw1r0[8], gw1r1[8], gb1r[8];
  #pragma unroll
  for (int kk = 0; kk < 8; ++kk){
    int k = k8 + kk;
    fw1r0[kk] = ldany(fw1, k,       isbf);
    fw1r1[kk] = ldany(fw1, H + k,   isbf);
    fw1r2[kk] = ldany(fw1, 2*H + k, isbf);
    fb1r[kk]  = ldany(fb1, k,       isbf);
    gw1r0[kk] = ldany(gw1, k,       isbf);
    gw1r1[kk] = ldany(gw1, H + k,   isbf);
    gb1r[kk]  = ldany(gb1, k,       isbf);
  }
  const float fb3r0 = ldany(fb3, 0, isbf), fb3r1 = ldany(fb3, 1, isbf);
  const float gb3r0 = ldany(gb3, 0, isbf), gb3r1 = ldany(gb3, 1, isbf);

  // ---------- y in registers (redundant across the 16 lanes sharing a path) ----------
  float ycur0 = ldany(y0, (long long)gp*2 + 0, isbf);
  float ycur1 = ldany(y0, (long long)gp*2 + 1, isbf);
  if (w < 2 && lane < 16){                       // one store per path
    size_t r = (size_t)gp * TLEN;
    if (isbf) ((unsigned*)out)[r] = (unsigned)f2bf(ycur0) | ((unsigned)f2bf(ycur1) << 16);
    else      ((float2*)out)[r]   = make_float2(ycur0, ycur1);
  }
  float2 dwcur;
  {
    long long e = (long long)gp * 2;             // t = 0
    if (isbf){ unsigned u = *(const unsigned*)((const unsigned short*)dW + e);
               dwcur = make_float2(bf2f(u & 0xffffu), bf2f(u >> 16)); }
    else       dwcur = *(const float2*)((const float*)dW + e);
  }
  __syncthreads();

  const float* TSf = (const float*)(sm + O_TS);

  for (int t = 0; t < TLEN - 1; ++t){
    float dt = TSf[t+1] - TSf[t];
    float sqdt = sqrtf(dt);

    // prefetch next-step dW for this lane's path
    float2 dwnext;
    {
      int tn = (t + 1 <= TLEN - 2) ? t + 1 : TLEN - 2;
      long long e = ((long long)tn * NPATH + gp) * 2;
      if (isbf){ unsigned u = *(const unsigned*)((const unsigned short*)dW + e);
                 dwnext = make_float2(bf2f(u & 0xffffu), bf2f(u >> 16)); }
      else       dwnext = *(const float2*)((const float*)dW + e);
    }

    // ---- S0: layer 1 (drift + diffusion) for (path p1, 8 k's), split hi/lo ----
    {
      float ysp = ycur0 - ycur1;
      unsigned short fh[8], fl[8], gh[8], gl[8];
      #pragma unroll
      for (int kk = 0; kk < 8; ++kk){
        float hf = fsilu(fb1r[kk] + ycur0*fw1r0[kk] + ycur1*fw1r1[kk] + ysp*fw1r2[kk]);
        float hg = fsilu(gb1r[kk] + ycur0*gw1r0[kk] + ycur1*gw1r1[kk]);
        split2(hf, fh[kk], fl[kk]);
        split2(hg, gh[kk], gl[kk]);
      }
      st8(sm + O_BFH, p1, k8, fh);
      st8(sm + O_BFL, p1, k8, fl);
      st8(sm + O_BGH, p1, k8, gh);
      st8(sm + O_BGL, p1, k8, gl);
    }
    __syncthreads();                                     // A: acts ready

    // ---- S1: fwd MFMAs (f and g) + head partials ----
    f32x4 accg[2];
    {
      f32x4 accf[2];
      accf[0] = (f32x4)0.f; accf[1] = (f32x4)0.f;
      accg[0] = (f32x4)0.f; accg[1] = (f32x4)0.f;
      #pragma unroll
      for (int kt = 0; kt < 4; ++kt){
        int colk = kt*32 + q*8;
        bf16x8 af0 = ldfrag(sm + O_WF2T, 32*wp + m16,      colk);
        bf16x8 af1 = ldfrag(sm + O_WF2T, 32*wp + 16 + m16, colk);
        bf16x8 bfh = ldfrag(sm + O_BFH, p1, colk);
        bf16x8 bfl = ldfrag(sm + O_BFL, p1, colk);
        accf[0] = MFMA(af0, bfl, accf[0]); accf[0] = MFMA(af0, bfh, accf[0]);
        accf[1] = MFMA(af1, bfl, accf[1]); accf[1] = MFMA(af1, bfh, accf[1]);
        bf16x8 ag0 = ldfrag(sm + O_WG2T, 32*wp + m16,      colk);
        bf16x8 ag1 = ldfrag(sm + O_WG2T, 32*wp + 16 + m16, colk);
        bf16x8 bgh = ldfrag(sm + O_BGH, p1, colk);
        bf16x8 bgl = ldfrag(sm + O_BGL, p1, colk);
        accg[0] = MFMA(ag0, bgl, accg[0]); accg[0] = MFMA(ag0, bgh, accg[0]);
        accg[1] = MFMA(ag1, bgl, accg[1]); accg[1] = MFMA(ag1, bgh, accg[1]);
      }
      float pf0 = 0, pf1 = 0, pr0 = 0, pr1 = 0;
      #pragma unroll
      for (int mi = 0; mi < 2; ++mi)
        #pragma unroll
        for (int r = 0; r < 4; ++r){
          int i = mi*4 + r;
          float vf = fsilu(accf[mi][r] + fb2r[i]);
          pf0 += vf * w3f0[i];
          pf1 += vf * w3f1[i];
          float zg = accg[mi][r] + gb2r[i];
          accg[mi][r] = zg;                    // keep biased z2g for S3
          float vg = fsilu(zg);
          pr0 += vg * w3g0[i];
          pr1 += vg * w3g1[i];
        }
      pf0 += __shfl_xor(pf0, 16, 64); pf0 += __shfl_xor(pf0, 32, 64);
      pf1 += __shfl_xor(pf1, 16, 64); pf1 += __shfl_xor(pf1, 32, 64);
      pr0 += __shfl_xor(pr0, 16, 64); pr0 += __shfl_xor(pr0, 32, 64);
      pr1 += __shfl_xor(pr1, 16, 64); pr1 += __shfl_xor(pr1, 32, 64);
      if (lane < 16){
        *(float2*)(sm + O_PF   + (wp*32 + p1)*8) = make_float2(pf0, pf1);
        *(float2*)(sm + O_PRAW + (wp*32 + p1)*8) = make_float2(pr0, pr1);
      }
    }
    __syncthreads();                                     // B: partials ready

    // ---- S2': every lane combines raw for ITS path -> g, cr (registers) ----
    float g0, g1, dw0, dw1, cr0, cr1;
    {
      float raw0 = gb3r0, raw1 = gb3r1;
      #pragma unroll
      for (int w2 = 0; w2 < 4; ++w2){
        float2 v = *(const float2*)(sm + O_PRAW + (w2*32 + p1)*8);
        raw0 += v.x; raw1 += v.y;
      }
      dw0 = dwcur.x * sqdt; dw1 = dwcur.y * sqdt;
      float vv0 = 0.5f*(dw0*dw0 - dt), vv1 = 0.5f*(dw1*dw1 - dt);
      float sp0 = fsoftplus(raw0), sp1 = fsoftplus(raw1);
      g0 = fminf(fmaxf(sp0, 1e-4f), 5.0f);
      g1 = fminf(fmaxf(sp1, 1e-4f), 5.0f);
      float m0 = (sp0 > 1e-4f && sp0 < 5.0f) ? 1.0f : 0.0f;
      float m1 = (sp1 > 1e-4f && sp1 < 5.0f) ? 1.0f : 0.0f;
      cr0 = vv0 * (g0 * fsig(raw0) * m0);
      cr1 = vv1 * (g1 * fsig(raw1) * m1);
    }

    // ---- S3: cotangent seed c2 -> BFH/BFL (reuse) ----
    #pragma unroll
    for (int mi = 0; mi < 2; ++mi){
      unsigned short hi[4], lo[4];
      #pragma unroll
      for (int r = 0; r < 4; ++r){
        int i = mi*4 + r;
        float c2 = (cr0 * w3g0[i] + cr1 * w3g1[i]) * fsilud(accg[mi][r]);
        split2(c2, hi[r], lo[r]);
      }
      st4(sm + O_BFH, p1, 32*wp + 16*mi + q*4, hi);
      st4(sm + O_BFL, p1, 32*wp + 16*mi + q*4, lo);
    }
    __syncthreads();                                     // D: c2 ready

    // ---- S4: backward MFMA (c1 = gw2 @ c2) + corr head partials ----
    {
      f32x4 accc[2];
      accc[0] = (f32x4)0.f; accc[1] = (f32x4)0.f;
      #pragma unroll
      for (int kt = 0; kt < 4; ++kt){
        int colk = kt*32 + q*8;
        bf16x8 a0 = ldfrag(sm + O_WG2R, 32*wp + m16,      colk);
        bf16x8 a1 = ldfrag(sm + O_WG2R, 32*wp + 16 + m16, colk);
        bf16x8 bh = ldfrag(sm + O_BFH, p1, colk);
        bf16x8 bl = ldfrag(sm + O_BFL, p1, colk);
        accc[0] = MFMA(a0, bl, accc[0]); accc[0] = MFMA(a0, bh, accc[0]);
        accc[1] = MFMA(a1, bl, accc[1]); accc[1] = MFMA(a1, bh, accc[1]);
      }
      float pc0 = 0, pc1 = 0;
      #pragma unroll
      for (int mi = 0; mi < 2; ++mi)
        #pragma unroll
        for (int r = 0; r < 4; ++r){
          int i = mi*4 + r;
          float z1 = gb1b[i] + ycur0*gw1b0[i] + ycur1*gw1b1[i];
          float u  = accc[mi][r] * fsilud(z1);
          pc0 += u * gw1b0[i];
          pc1 += u * gw1b1[i];
        }
      pc0 += __shfl_xor(pc0, 16, 64); pc0 += __shfl_xor(pc0, 32, 64);
      pc1 += __shfl_xor(pc1, 16, 64); pc1 += __shfl_xor(pc1, 32, 64);
      if (lane < 16)
        *(float2*)(sm + O_PCORR + (wp*32 + p1)*8) = make_float2(pc0, pc1);
    }
    __syncthreads();                                     // E: corr partials ready

    // ---- S5: Milstein update (redundant per lane) + output ----
    {
      float f0 = fb3r0, f1 = fb3r1, c0 = 0.f, c1 = 0.f;
      #pragma unroll
      for (int w2 = 0; w2 < 4; ++w2){
        float2 a = *(const float2*)(sm + O_PF    + (w2*32 + p1)*8);
        float2 b = *(const float2*)(sm + O_PCORR + (w2*32 + p1)*8);
        f0 += a.x; f1 += a.y; c0 += b.x; c1 += b.y;
      }
      ycur0 += f0*dt + g0*dw0 + c0;
      ycur1 += f1*dt + g1*dw1 + c1;
      if (w < 2 && lane < 16){
        size_t r = (size_t)gp * TLEN + (t + 1);
        if (isbf) ((unsigned*)out)[r] = (unsigned)f2bf(ycur0) | ((unsigned)f2bf(ycur1) << 16);
        else      ((float2*)out)[r]   = make_float2(ycur0, ycur1);
      }
      dwcur = dwnext;
    }
  }
}

extern "C" void kernel_launch(void* const* d_in, const int* in_sizes, int n_in,
                              void* d_out, int out_size, void* d_ws, size_t ws_size,
                              hipStream_t stream)
{
  (void)in_sizes; (void)n_in; (void)out_size; (void)d_ws; (void)ws_size;
  hipFuncSetAttribute((const void*)GeneratorSDE_kernel,
                      hipFuncAttributeMaxDynamicSharedMemorySize, SMEM_BYTES);
  GeneratorSDE_kernel<<<dim3(NPATH / BP), dim3(NTHR), SMEM_BYTES, stream>>>(
      d_in[0], d_in[1], d_in[2],
      d_in[3], d_in[4], d_in[5], d_in[6], d_in[7], d_in[8],
      d_in[9], d_in[10], d_in[11], d_in[12], d_in[13], d_in[14],
      d_out);
}